// Round 10
// baseline (8978.893 us; speedup 1.0000x reference)
//
#include <hip/hip_runtime.h>
#include <stdint.h>

// ---------------- problem constants ----------------
#define B_     1024
#define F_     512
#define H_     1024
#define S_     8
#define BOX_   12
#define MAXB_  64
#define MAXSY_ 64
#define L_     126
#define STK_   3

#define LSTR   1040          // LDS panel row stride in u16 (1024 + 16 pad)

typedef unsigned short u16;
typedef unsigned int   u32;
typedef __attribute__((ext_vector_type(8))) short sh8;   // 8 bf16 (4 VGPRs)
typedef __attribute__((ext_vector_type(4))) int   i4;    // 16 B payload
typedef __attribute__((ext_vector_type(4))) float f4;    // MFMA accumulator

#define MFMA16(a,b,c) __builtin_amdgcn_mfma_f32_16x16x32_bf16((a),(b),(c),0,0,0)

// ---------------- ws layout (bytes) — row-major planes (round-6 verified) --------
constexpr size_t PL_HF = (size_t)H_ * F_ * 2;
constexpr size_t PL_FH = (size_t)F_ * H_ * 2;
constexpr size_t PL_SS = 16384;
constexpr size_t PL_BX = 16384;
constexpr size_t O_WdHi  = 8192;                  // first 8 KB = barrier counters
constexpr size_t O_WdLo  = O_WdHi  + PL_HF;
constexpr size_t O_WsdHi = O_WdLo  + PL_HF;
constexpr size_t O_WsdLo = O_WsdHi + PL_HF;
constexpr size_t O_WlHi  = O_WsdLo + PL_HF;
constexpr size_t O_WlLo  = O_WlHi  + PL_FH;
constexpr size_t O_WrHi  = O_WlLo  + PL_FH;
constexpr size_t O_WrLo  = O_WrHi  + PL_FH;
constexpr size_t O_WsfHi = O_WrLo  + PL_FH;
constexpr size_t O_WsfLo = O_WsfHi + PL_FH;
constexpr size_t O_WssHi = O_WsfLo + PL_FH;
constexpr size_t O_WssLo = O_WssHi + PL_SS;
constexpr size_t O_WbxHi = O_WssLo + PL_SS;
constexpr size_t O_WbxLo = O_WbxHi + PL_BX;
constexpr size_t SZ_STK  = (size_t)B_ * STK_ * F_ * 2;   // [e][slot][512]
constexpr size_t O_SHi   = O_WbxLo + PL_BX;
constexpr size_t O_SLo   = O_SHi   + SZ_STK;
constexpr size_t SZ_H    = (size_t)B_ * H_ * 2;          // [e][1024]
constexpr size_t O_HAHi  = O_SLo   + SZ_STK;
constexpr size_t O_HALo  = O_HAHi  + SZ_H;
constexpr size_t O_HSHi  = O_HALo  + SZ_H;
constexpr size_t O_HSLo  = O_HSHi  + SZ_H;
constexpr size_t WS_NEED = O_HSLo  + SZ_H;               // ~24.1 MB

// ---------------- numeric helpers ----------------
__device__ __forceinline__ float bf2float(u16 h) {
    union { u32 u; float f; } v; v.u = ((u32)h) << 16; return v.f;
}
__device__ __forceinline__ u16 bfhi_of(float f) {           // RNE fp32->bf16
    union { float f; u32 u; } v; v.f = f;
    u32 u = v.u;
    return (u16)((u + 0x7fffu + ((u >> 16) & 1u)) >> 16);
}
__device__ __forceinline__ void split2(float x, u16& hi, u16& lo) {
    hi = bfhi_of(x);
    lo = bfhi_of(x - bf2float(hi));
}

// ---------------- device-coherent (sc0 sc1) ops, fence-free (round-6 verified) ----
__device__ __forceinline__ void cload8(i4& d0, i4& d1, i4& d2, i4& d3,
                                       i4& d4, i4& d5, i4& d6, i4& d7,
    const u16* p0, const u16* p1, const u16* p2, const u16* p3,
    const u16* p4, const u16* p5, const u16* p6, const u16* p7)
{
    asm volatile(
        "global_load_dwordx4 %0, %8, off sc0 sc1\n\t"
        "global_load_dwordx4 %1, %9, off sc0 sc1\n\t"
        "global_load_dwordx4 %2, %10, off sc0 sc1\n\t"
        "global_load_dwordx4 %3, %11, off sc0 sc1\n\t"
        "global_load_dwordx4 %4, %12, off sc0 sc1\n\t"
        "global_load_dwordx4 %5, %13, off sc0 sc1\n\t"
        "global_load_dwordx4 %6, %14, off sc0 sc1\n\t"
        "global_load_dwordx4 %7, %15, off sc0 sc1\n\t"
        "s_waitcnt vmcnt(0)"
        : "=&v"(d0),"=&v"(d1),"=&v"(d2),"=&v"(d3),
          "=&v"(d4),"=&v"(d5),"=&v"(d6),"=&v"(d7)
        : "v"(p0),"v"(p1),"v"(p2),"v"(p3),"v"(p4),"v"(p5),"v"(p6),"v"(p7));
}
__device__ __forceinline__ void cload4(i4& d0, i4& d1, i4& d2, i4& d3,
    const u16* p0, const u16* p1, const u16* p2, const u16* p3)
{
    asm volatile(
        "global_load_dwordx4 %0, %4, off sc0 sc1\n\t"
        "global_load_dwordx4 %1, %5, off sc0 sc1\n\t"
        "global_load_dwordx4 %2, %6, off sc0 sc1\n\t"
        "global_load_dwordx4 %3, %7, off sc0 sc1\n\t"
        "s_waitcnt vmcnt(0)"
        : "=&v"(d0),"=&v"(d1),"=&v"(d2),"=&v"(d3)
        : "v"(p0),"v"(p1),"v"(p2),"v"(p3));
}
__device__ __forceinline__ void cstore2(u16* p, u16 v) {
    asm volatile("global_store_short %0, %1, off sc0 sc1"
                 :: "v"(p), "v"((u32)v) : "memory");
}
__device__ __forceinline__ void vdrain() {
    asm volatile("s_waitcnt vmcnt(0)" ::: "memory");
}
__device__ __forceinline__ sh8 as_sh8(i4 v) { return __builtin_bit_cast(sh8, v); }

// ---------------- prep: split weights + X into row-major planes (verified) -------
__device__ void split_range(const float* __restrict__ s, u16* hi, u16* lo,
                            int n, int t0, int stride) {
    for (int i = t0; i < n; i += stride) {
        float v = s[i];
        u16 h = bfhi_of(v);
        hi[i] = h;
        lo[i] = bfhi_of(v - bf2float(h));
    }
}

__global__ void grass_prep(const float* __restrict__ X,
                           const float* __restrict__ Wd, const float* __restrict__ Wl,
                           const float* __restrict__ Wr, const float* __restrict__ Wsd,
                           const float* __restrict__ Wsf, const float* __restrict__ Wss,
                           const float* __restrict__ Wbox, char* __restrict__ ws)
{
    const int t0 = blockIdx.x * blockDim.x + threadIdx.x;
    const int st = gridDim.x * blockDim.x;
    split_range(Wd,  (u16*)(ws + O_WdHi),  (u16*)(ws + O_WdLo),  H_ * F_, t0, st);
    split_range(Wsd, (u16*)(ws + O_WsdHi), (u16*)(ws + O_WsdLo), H_ * F_, t0, st);
    split_range(Wl,  (u16*)(ws + O_WlHi),  (u16*)(ws + O_WlLo),  F_ * H_, t0, st);
    split_range(Wr,  (u16*)(ws + O_WrHi),  (u16*)(ws + O_WrLo),  F_ * H_, t0, st);
    split_range(Wsf, (u16*)(ws + O_WsfHi), (u16*)(ws + O_WsfLo), F_ * H_, t0, st);
    split_range(Wss, (u16*)(ws + O_WssHi), (u16*)(ws + O_WssLo), S_ * H_, t0, st);
    split_range(Wbox,(u16*)(ws + O_WbxHi), (u16*)(ws + O_WbxLo), BOX_ * F_, t0, st);
    u16* SHi = (u16*)(ws + O_SHi);
    u16* SLo = (u16*)(ws + O_SLo);
    for (int i = t0; i < B_ * F_; i += st) {
        int e = i >> 9, k = i & (F_ - 1);
        float v = X[i];
        u16 h = bfhi_of(v);
        size_t off = (size_t)e * STK_ * F_ + k;   // slot 0
        SHi[off] = h;
        SLo[off] = bfhi_of(v - bf2float(h));
    }
}

// -------- fence-free group barrier (full wait; verified rounds 6/8) --------
__device__ __forceinline__ void gbar(int* bar, int target) {
    vdrain();
    __syncthreads();
    if (threadIdx.x == 0) {
        __hip_atomic_fetch_add(bar, 1, __ATOMIC_RELAXED, __HIP_MEMORY_SCOPE_AGENT);
        while (__hip_atomic_load(bar, __ATOMIC_RELAXED, __HIP_MEMORY_SCOPE_AGENT) < target)
            __builtin_amdgcn_s_sleep(2);
    }
    __syncthreads();
}

// ---------------- cooperative panel staging: 16 rows x K (hi+lo) -> LDS ----------
// rowOff[row]: element offset of row's vector in the global plane. Addresses are
// wave-contiguous within a row -> fully packed 64B lines on the coherent path.
__device__ __forceinline__ void stage16(const u16* __restrict__ gHi, const u16* __restrict__ gLo,
                                        const int* rowOff, u16* lHi, u16* lLo,
                                        int K, int tid)
{
    const int cprLog = (K == 1024) ? 7 : 6;    // 16B chunks per row (128 / 64)
    const int iters  = (16 << cprLog) >> 8;    // 8 (K=1024) or 4 (K=512)
    for (int i = 0; i < iters; i += 4) {
        const u16* ph[4]; const u16* pl[4]; int la[4];
#pragma unroll
        for (int q = 0; q < 4; ++q) {
            int c   = tid + (i + q) * 256;
            int row = c >> cprLog;
            int kc  = (c & ((1 << cprLog) - 1)) << 3;
            ph[q] = gHi + rowOff[row] + kc;
            pl[q] = gLo + rowOff[row] + kc;
            la[q] = row * LSTR + kc;
        }
        i4 d0,d1,d2,d3,d4,d5,d6,d7;
        cload8(d0,d1,d2,d3,d4,d5,d6,d7,
               ph[0],ph[1],ph[2],ph[3], pl[0],pl[1],pl[2],pl[3]);
        *(i4*)(lHi + la[0]) = d0; *(i4*)(lHi + la[1]) = d1;
        *(i4*)(lHi + la[2]) = d2; *(i4*)(lHi + la[3]) = d3;
        *(i4*)(lLo + la[0]) = d4; *(i4*)(lLo + la[1]) = d5;
        *(i4*)(lLo + la[2]) = d6; *(i4*)(lLo + la[3]) = d7;
    }
}

// ---------------- 16x64 GEMM per wave from LDS A (c[4] n-frags) -------------------
// wave wv covers cols nBase + wv*64 .. +63; all waves share the 16-row LDS panel.
__device__ __forceinline__ void gemmL(const u16* lHi, const u16* lLo,
                                      const u16* __restrict__ WHi, const u16* __restrict__ WLo,
                                      int nBase, int K, f4 c[4], int lane, int wv)
{
    const int quad = lane >> 4, mr = lane & 15;
    const int n0 = nBase + wv * 64 + mr;
    const u16* bh = WHi + (size_t)n0 * K;
    const u16* bl = WLo + (size_t)n0 * K;
    f4 z = {0.f,0.f,0.f,0.f};
    c[0]=z; c[1]=z; c[2]=z; c[3]=z;
    for (int kb = 0; kb < K; kb += 32) {
        const int kq = kb + quad * 8;
        sh8 aH = *(const sh8*)(lHi + mr * LSTR + kq);
        sh8 aL = *(const sh8*)(lLo + mr * LSTR + kq);
#pragma unroll
        for (int nt = 0; nt < 4; ++nt) {
            const u16* bhn = bh + (size_t)nt * 16 * K;
            const u16* bln = bl + (size_t)nt * 16 * K;
            sh8 bH = *(const sh8*)(bhn + kq);
            sh8 bL = *(const sh8*)(bln + kq);
            c[nt] = MFMA16(aH, bH, c[nt]);
            c[nt] = MFMA16(aH, bL, c[nt]);
            c[nt] = MFMA16(aL, bH, c[nt]);
        }
    }
}

// 16 x (<=16) from LDS A (single wave; caller guards wv==0)
__device__ __forceinline__ void gemm16L(const u16* lHi, const u16* lLo,
                                        const u16* __restrict__ WHi, const u16* __restrict__ WLo,
                                        int nValid, int K, f4& c, int lane)
{
    const int quad = lane >> 4, mr = lane & 15;
    const bool nb = (mr < nValid);
    const u16* bh = WHi + (size_t)mr * K;
    const u16* bl = WLo + (size_t)mr * K;
    f4 z = {0.f,0.f,0.f,0.f}; c = z;
    for (int kb = 0; kb < K; kb += 32) {
        const int kq = kb + quad * 8;
        sh8 aH = *(const sh8*)(lHi + mr * LSTR + kq);
        sh8 aL = *(const sh8*)(lLo + mr * LSTR + kq);
        sh8 bH = {0,0,0,0,0,0,0,0}, bL = {0,0,0,0,0,0,0,0};
        if (nb) { bH = *(const sh8*)(bh + kq); bL = *(const sh8*)(bl + kq); }
        c = MFMA16(aH, bH, c);
        c = MFMA16(aH, bL, c);
        c = MFMA16(aL, bH, c);
    }
}

// 16 x (<=16) from GLOBAL A via per-row offsets (round-6 verified pattern)
__device__ __forceinline__ void gemm16G(const u16* __restrict__ AHi, const u16* __restrict__ ALo,
                                        const int* aOff,
                                        const u16* __restrict__ WHi, const u16* __restrict__ WLo,
                                        int nValid, int K, f4& c, int lane)
{
    const int quad = lane >> 4, mr = lane & 15;
    const int ao = aOff[mr];
    const bool nb = (mr < nValid);
    const u16* bh = WHi + (size_t)mr * K;
    const u16* bl = WLo + (size_t)mr * K;
    f4 z = {0.f,0.f,0.f,0.f}; c = z;
    for (int kb = 0; kb < K; kb += 64) {
        const int k0 = kb + quad * 8, k1 = k0 + 32;
        sh8 bH0 = {0,0,0,0,0,0,0,0}, bL0 = {0,0,0,0,0,0,0,0};
        sh8 bH1 = {0,0,0,0,0,0,0,0}, bL1 = {0,0,0,0,0,0,0,0};
        if (nb) {
            bH0 = *(const sh8*)(bh + k0); bL0 = *(const sh8*)(bl + k0);
            bH1 = *(const sh8*)(bh + k1); bL1 = *(const sh8*)(bl + k1);
        }
        i4 a0,a1,a2,a3;
        cload4(a0,a1,a2,a3, AHi+ao+k0, ALo+ao+k0, AHi+ao+k1, ALo+ao+k1);
        sh8 aH0=as_sh8(a0), aL0=as_sh8(a1), aH1=as_sh8(a2), aL1=as_sh8(a3);
        c = MFMA16(aH0, bH0, c);
        c = MFMA16(aH0, bL0, c);
        c = MFMA16(aL0, bH0, c);
        c = MFMA16(aH1, bH1, c);
        c = MFMA16(aH1, bL1, c);
        c = MFMA16(aL1, bH1, c);
    }
}

// 16-row x 64-col GEMM from GLOBAL A (mixed-op fallback path; c[4])
__device__ __forceinline__ void gemmG(const u16* __restrict__ AHi, const u16* __restrict__ ALo,
                                      const int* aOff,
                                      const u16* __restrict__ WHi, const u16* __restrict__ WLo,
                                      int nBase, int K, f4 c[4], int lane, int wv)
{
    const int quad = lane >> 4, mr = lane & 15;
    const int ao = aOff[mr];
    const int n0 = nBase + wv * 64 + mr;
    const u16* bh = WHi + (size_t)n0 * K;
    const u16* bl = WLo + (size_t)n0 * K;
    f4 z = {0.f,0.f,0.f,0.f};
    c[0]=z; c[1]=z; c[2]=z; c[3]=z;
    for (int kb = 0; kb < K; kb += 64) {
        const int k0 = kb + quad * 8, k1 = k0 + 32;
        i4 a0,a1,a2,a3;
        cload4(a0,a1,a2,a3, AHi+ao+k0, ALo+ao+k0, AHi+ao+k1, ALo+ao+k1);
        sh8 aH0=as_sh8(a0), aL0=as_sh8(a1), aH1=as_sh8(a2), aL1=as_sh8(a3);
#pragma unroll
        for (int nt = 0; nt < 4; ++nt) {
            const u16* bhn = bh + (size_t)nt * 16 * K;
            const u16* bln = bl + (size_t)nt * 16 * K;
            sh8 bH0 = *(const sh8*)(bhn + k0), bL0 = *(const sh8*)(bln + k0);
            sh8 bH1 = *(const sh8*)(bhn + k1), bL1 = *(const sh8*)(bln + k1);
            c[nt] = MFMA16(aH0, bH0, c[nt]);
            c[nt] = MFMA16(aH0, bL0, c[nt]);
            c[nt] = MFMA16(aL0, bH0, c[nt]);
            c[nt] = MFMA16(aH1, bH1, c[nt]);
            c[nt] = MFMA16(aH1, bL1, c[nt]);
            c[nt] = MFMA16(aL1, bH1, c[nt]);
        }
    }
}

// ---------------- epilogues (C/D map: col=lane&15, row=(lane>>4)*4+reg) ----------
__device__ __forceinline__ void epH(const f4 c[4], const float* __restrict__ bias,
                                    int nBase, int e0, u16* DHi, u16* DLo,
                                    int lane, int wv)
{
    const int quad = lane >> 4, mr = lane & 15;
#pragma unroll
    for (int nt = 0; nt < 4; ++nt) {
        const int nn = nBase + wv * 64 + nt * 16 + mr;
        const float bb = bias[nn];
#pragma unroll
        for (int r = 0; r < 4; ++r) {
            int mm = quad * 4 + r;
            float v = tanhf(c[nt][r] + bb);
            u16 hi, lo; split2(v, hi, lo);
            size_t off = (size_t)(e0 + mm) * H_ + nn;
            cstore2(DHi + off, hi);
            cstore2(DLo + off, lo);
        }
    }
}

__device__ __forceinline__ void epStack(const f4 c[4], const float* __restrict__ bias,
                                        int nBase, int opSel, bool useRi, int tix, int e0,
                                        const int* opsL, const int* spA,
                                        u16* SHi, u16* SLo, int lane, int wv)
{
    const int quad = lane >> 4, mr = lane & 15;
#pragma unroll
    for (int nt = 0; nt < 4; ++nt) {
        const int nn = nBase + wv * 64 + nt * 16 + mr;
        const float bb = bias[nn];
#pragma unroll
        for (int r = 0; r < 4; ++r) {
            int mm = quad * 4 + r;
            if (opsL[mm * L_ + tix] != opSel) continue;
            int sp = spA[mm];
            int slot = useRi ? sp : sp - 1;
            slot = slot < 0 ? 0 : (slot > STK_ - 1 ? STK_ - 1 : slot);
            float v = tanhf(c[nt][r] + bb);
            u16 hi, lo; split2(v, hi, lo);
            size_t off = ((size_t)(e0 + mm) * STK_ + slot) * F_ + nn;
            cstore2(SHi + off, hi);
            cstore2(SLo + off, lo);
        }
    }
}

__device__ __forceinline__ void ep_small16(const f4& c, const float* __restrict__ bias,
                                           int nValid, int opSel, int tix, int e0,
                                           const int* opsL, const int* eCnt, const int* eTot,
                                           float* __restrict__ outBase, int rowStride, int ncols,
                                           int lane)
{
    const int nn = lane & 15;
    if (nn >= nValid) return;
#pragma unroll
    for (int r = 0; r < 4; ++r) {
        int mm = (lane >> 4) * 4 + r;
        if (opsL[mm * L_ + tix] != opSel) continue;
        int slot = eTot[mm] - 1 - eCnt[mm];
        if (slot < 0 || slot >= 64) continue;
        float v = tanhf(c[r] + bias[nn]);
        outBase[(size_t)(e0 + mm) * rowStride + slot * ncols + nn] = v;  // host-only reader
    }
}

// ------- main: 64 groups (16 rows) x 4 blocks (N=256). grid 256, 1 block/CU. ------
// Swizzle: p = (gid&7) + 8*j + 32*(gid>>3) -> a group's 4 blocks share p%8 (one XCD
// under the round-robin heuristic). gid = (p&7) + 8*(p>>5); j = (p>>3)&3.
__global__ __launch_bounds__(256, 2) void grass_main(
    const int* __restrict__ ops,
    const float* __restrict__ bd, const float* __restrict__ bl, const float* __restrict__ br,
    const float* __restrict__ bsd, const float* __restrict__ bsf, const float* __restrict__ bss,
    const float* __restrict__ bbox,
    char* __restrict__ ws, float* __restrict__ out)
{
    const int tid  = threadIdx.x;
    const int lane = tid & 63, wv = tid >> 6;
    const int p    = blockIdx.x;
    const int gid  = (p & 7) + 8 * (p >> 5);
    const int j    = (p >> 3) & 3;
    const int e0   = gid * 16;

    const u16* WdHi  = (const u16*)(ws + O_WdHi);
    const u16* WdLo  = (const u16*)(ws + O_WdLo);
    const u16* WsdHi = (const u16*)(ws + O_WsdHi);
    const u16* WsdLo = (const u16*)(ws + O_WsdLo);
    const u16* WlHi  = (const u16*)(ws + O_WlHi);
    const u16* WlLo  = (const u16*)(ws + O_WlLo);
    const u16* WrHi  = (const u16*)(ws + O_WrHi);
    const u16* WrLo  = (const u16*)(ws + O_WrLo);
    const u16* WsfHi = (const u16*)(ws + O_WsfHi);
    const u16* WsfLo = (const u16*)(ws + O_WsfLo);
    const u16* WssHi = (const u16*)(ws + O_WssHi);
    const u16* WssLo = (const u16*)(ws + O_WssLo);
    const u16* WbxHi = (const u16*)(ws + O_WbxHi);
    const u16* WbxLo = (const u16*)(ws + O_WbxLo);
    u16* SHi  = (u16*)(ws + O_SHi);
    u16* SLo  = (u16*)(ws + O_SLo);
    u16* HAHi = (u16*)(ws + O_HAHi);
    u16* HALo = (u16*)(ws + O_HALo);
    u16* HSHi = (u16*)(ws + O_HSHi);
    u16* HSLo = (u16*)(ws + O_HSLo);
    int* bar = (int*)ws + gid * 32;   // 128 B spacing; 64 groups * 128 B = 8 KB

    float* outB = out;                                   // [B][MAXB][BOX]
    float* outS = out + (size_t)B_ * MAXB_ * BOX_;       // [B][MAXSY][S]

    __shared__ u16 lHi[16 * LSTR];    // staged A panel (hi), 16 rows
    __shared__ u16 lLo[16 * LSTR];
    __shared__ int opsL[16 * L_];
    __shared__ int spA[16], beA[16], seA[16], beF[16], seF[16];
    __shared__ int aStk[16], aHH[16];
    __shared__ int sInfo[2];          // op, uniform

    for (int idx = tid; idx < 16 * L_; idx += 256) {
        int e = idx / L_, t = idx - e * L_;
        opsL[idx] = ops[(size_t)(e0 + e) * L_ + t];
    }
    __syncthreads();
    if (tid < 16) {
        spA[tid] = 1; beA[tid] = 0; seA[tid] = 0;
        int cb = 0, cs = 0;
        for (int t = 0; t < L_; ++t) {
            int o = opsL[tid * L_ + t];
            cb += (o == 0); cs += (o == 2);
        }
        beF[tid] = cb; seF[tid] = cs;
        aHH[tid]  = (e0 + tid) * H_;
        aStk[tid] = ((e0 + tid) * STK_ + 0) * F_;
    }
    __syncthreads();

    int epoch = 0;
    f4 c[4];
    f4 cs;

    for (int step = 0; step < L_; ++step) {
        const int tix = L_ - 1 - step;   // processing order = reverse of stored
        if (wv == 0) {
            int o  = opsL[(lane & 15) * L_ + tix];
            int sp = spA[lane & 15];
            unsigned long long bo = __ballot(o  == opsL[0 * L_ + tix]);
            unsigned long long bs = __ballot(sp == spA[0]);
            if (lane == 0) {
                sInfo[0] = o;
                sInfo[1] = (bo == ~0ull && bs == ~0ull) ? 1 : 0;
            }
        }
        __syncthreads();
        const int opU = sInfo[0], uni = sInfo[1];

        if (uni) {
            if (opU == 1) {
                stage16(SHi, SLo, aStk, lHi, lLo, F_, tid);
                __syncthreads();
                gemmL(lHi, lLo, WdHi, WdLo, j * 256, F_, c, lane, wv);
                epH(c, bd, j * 256, e0, HAHi, HALo, lane, wv);
                ++epoch; gbar(bar, 4 * epoch);
                stage16(HAHi, HALo, aHH, lHi, lLo, H_, tid);
                __syncthreads();
                if (j < 2) {
                    gemmL(lHi, lLo, WlHi, WlLo, j * 256, H_, c, lane, wv);
                    epStack(c, bl, j * 256, 1, false, tix, e0, opsL, spA, SHi, SLo, lane, wv);
                } else {
                    gemmL(lHi, lLo, WrHi, WrLo, (j - 2) * 256, H_, c, lane, wv);
                    epStack(c, br, (j - 2) * 256, 1, true, tix, e0, opsL, spA, SHi, SLo, lane, wv);
                }
                ++epoch; gbar(bar, 4 * epoch);
            } else if (opU == 2) {
                stage16(SHi, SLo, aStk, lHi, lLo, F_, tid);
                __syncthreads();
                gemmL(lHi, lLo, WsdHi, WsdLo, j * 256, F_, c, lane, wv);
                epH(c, bsd, j * 256, e0, HAHi, HALo, lane, wv);
                ++epoch; gbar(bar, 4 * epoch);
                if (j < 2) {
                    stage16(HAHi, HALo, aHH, lHi, lLo, H_, tid);
                    __syncthreads();
                    gemmL(lHi, lLo, WsfHi, WsfLo, j * 256, H_, c, lane, wv);
                    epStack(c, bsf, j * 256, 2, false, tix, e0, opsL, spA, SHi, SLo, lane, wv);
                } else if (j == 2) {
                    stage16(HAHi, HALo, aHH, lHi, lLo, H_, tid);
                    __syncthreads();
                    if (wv == 0) {
                        gemm16L(lHi, lLo, WssHi, WssLo, S_, H_, cs, lane);
                        ep_small16(cs, bss, S_, 2, tix, e0, opsL, seA, seF,
                                   outS, MAXSY_ * S_, S_, lane);
                    }
                }
                ++epoch; gbar(bar, 4 * epoch);
            } else {
                // op0: box decode (block 0, wave 0); barrier closes the stack WAR
                if (j == 0 && wv == 0) {
                    gemm16G(SHi, SLo, aStk, WbxHi, WbxLo, BOX_, F_, cs, lane);
                    ep_small16(cs, bbox, BOX_, 0, tix, e0, opsL, beA, beF,
                               outB, MAXB_ * BOX_, BOX_, lane);
                }
                ++epoch; gbar(bar, 4 * epoch);
            }
        } else {
            // general (mixed-op) path: global-A GEMMs, compute all, select per row
            gemmG(SHi, SLo, aStk, WdHi, WdLo, j * 256, F_, c, lane, wv);
            epH(c, bd, j * 256, e0, HAHi, HALo, lane, wv);
            gemmG(SHi, SLo, aStk, WsdHi, WsdLo, j * 256, F_, c, lane, wv);
            epH(c, bsd, j * 256, e0, HSHi, HSLo, lane, wv);
            if (j == 0 && wv == 0) {
                gemm16G(SHi, SLo, aStk, WbxHi, WbxLo, BOX_, F_, cs, lane);
                ep_small16(cs, bbox, BOX_, 0, tix, e0, opsL, beA, beF,
                           outB, MAXB_ * BOX_, BOX_, lane);
            }
            ++epoch; gbar(bar, 4 * epoch);
            if (j < 2) {
                gemmG(HAHi, HALo, aHH, WlHi, WlLo, j * 256, H_, c, lane, wv);
                epStack(c, bl, j * 256, 1, false, tix, e0, opsL, spA, SHi, SLo, lane, wv);
                gemmG(HSHi, HSLo, aHH, WsfHi, WsfLo, j * 256, H_, c, lane, wv);
                epStack(c, bsf, j * 256, 2, false, tix, e0, opsL, spA, SHi, SLo, lane, wv);
            } else {
                gemmG(HAHi, HALo, aHH, WrHi, WrLo, (j - 2) * 256, H_, c, lane, wv);
                epStack(c, br, (j - 2) * 256, 1, true, tix, e0, opsL, spA, SHi, SLo, lane, wv);
                if (j == 2 && wv == 0) {
                    gemm16G(HSHi, HSLo, aHH, WssHi, WssLo, S_, H_, cs, lane);
                    ep_small16(cs, bss, S_, 2, tix, e0, opsL, seA, seF,
                               outS, MAXSY_ * S_, S_, lane);
                }
            }
            ++epoch; gbar(bar, 4 * epoch);
        }

        // per-row state update (block-local; all blocks identical)
        __syncthreads();
        if (tid < 16) {
            int o = opsL[tid * L_ + tix];
            if (o == 1)      spA[tid]++;
            else if (o == 2) seA[tid]++;
            else           { beA[tid]++; spA[tid]--; }
            int sp = spA[tid];
            int ti = sp - 1; ti = ti < 0 ? 0 : (ti > STK_ - 1 ? STK_ - 1 : ti);
            aStk[tid] = ((e0 + tid) * STK_ + ti) * F_;
        }
        __syncthreads();
    }
}

// ======================= fallback (round-3 fp32 kernel) =======================
__device__ __forceinline__ void fdot4(const float* __restrict__ row,
                                      const float* __restrict__ x0, const float* __restrict__ x1,
                                      const float* __restrict__ x2, const float* __restrict__ x3,
                                      int K4, float& r0, float& r1, float& r2, float& r3)
{
    const float4* r  = (const float4*)row;
    const float4* p0 = (const float4*)x0; const float4* p1 = (const float4*)x1;
    const float4* p2 = (const float4*)x2; const float4* p3 = (const float4*)x3;
    float s0=0.f,s1=0.f,s2=0.f,s3=0.f,t0=0.f,t1=0.f,t2=0.f,t3=0.f;
    for (int i = 0; i < K4; i += 2) {
        float4 w0 = r[i], w1 = r[i+1]; float4 v;
        v=p0[i]; s0+=w0.x*v.x; s0+=w0.y*v.y; s0+=w0.z*v.z; s0+=w0.w*v.w;
        v=p0[i+1]; t0+=w1.x*v.x; t0+=w1.y*v.y; t0+=w1.z*v.z; t0+=w1.w*v.w;
        v=p1[i]; s1+=w0.x*v.x; s1+=w0.y*v.y; s1+=w0.z*v.z; s1+=w0.w*v.w;
        v=p1[i+1]; t1+=w1.x*v.x; t1+=w1.y*v.y; t1+=w1.z*v.z; t1+=w1.w*v.w;
        v=p2[i]; s2+=w0.x*v.x; s2+=w0.y*v.y; s2+=w0.z*v.z; s2+=w0.w*v.w;
        v=p2[i+1]; t2+=w1.x*v.x; t2+=w1.y*v.y; t2+=w1.z*v.z; t2+=w1.w*v.w;
        v=p3[i]; s3+=w0.x*v.x; s3+=w0.y*v.y; s3+=w0.z*v.z; s3+=w0.w*v.w;
        v=p3[i+1]; t3+=w1.x*v.x; t3+=w1.y*v.y; t3+=w1.z*v.z; t3+=w1.w*v.w;
    }
    r0=s0+t0; r1=s1+t1; r2=s2+t2; r3=s3+t3;
}
__device__ __forceinline__ float fdot1(const float* __restrict__ row,
                                       const float* __restrict__ x, int K4)
{
    const float4* r = (const float4*)row; const float4* p = (const float4*)x;
    float s=0.f,t=0.f;
    for (int i = 0; i < K4; i += 2) {
        float4 w0=r[i], v0=p[i], w1=r[i+1], v1=p[i+1];
        s+=w0.x*v0.x; s+=w0.y*v0.y; s+=w0.z*v0.z; s+=w0.w*v0.w;
        t+=w1.x*v1.x; t+=w1.y*v1.y; t+=w1.z*v1.z; t+=w1.w*v1.w;
    }
    return s+t;
}
#define FB_G 4
__global__ __launch_bounds__(1024) void grass_fallback(
    const float* __restrict__ inputStacks, const int* __restrict__ ops,
    const float* __restrict__ Wd, const float* __restrict__ bd,
    const float* __restrict__ Wl, const float* __restrict__ bl,
    const float* __restrict__ Wr, const float* __restrict__ br,
    const float* __restrict__ Wsd, const float* __restrict__ bsd,
    const float* __restrict__ Wsf, const float* __restrict__ bsf,
    const float* __restrict__ Wss, const float* __restrict__ bss,
    const float* __restrict__ Wbox, const float* __restrict__ bbox,
    float* __restrict__ out)
{
    __shared__ float stk[FB_G][STK_][F_];
    __shared__ float hh[FB_G][H_];
    __shared__ float boxtmp[FB_G][MAXB_][BOX_];
    __shared__ float symtmp[FB_G][MAXSY_][S_];
    const int t = threadIdx.x, b0 = blockIdx.x * FB_G;
    for (int idx = t; idx < FB_G*F_; idx += 1024) {
        int g = idx >> 9, k = idx & (F_-1);
        stk[g][0][k] = inputStacks[(size_t)(b0+g)*F_ + k];
    }
    for (int idx = t; idx < FB_G*H_; idx += 1024) hh[idx>>10][idx&(H_-1)] = 0.f;
    int sp[FB_G], bc[FB_G], sc[FB_G];
#pragma unroll
    for (int g = 0; g < FB_G; ++g) { sp[g]=1; bc[g]=0; sc[g]=0; }
    __syncthreads();
    for (int step = 0; step < L_; ++step) {
        int op[FB_G], ti[FB_G], ri[FB_G]; bool a1=false,a2=false,a0=false;
#pragma unroll
        for (int g = 0; g < FB_G; ++g) {
            op[g] = ops[(size_t)(b0+g)*L_ + (L_-1-step)];
            int tt = sp[g]-1; tt = tt<0?0:(tt>STK_-1?STK_-1:tt); ti[g]=tt;
            int rr = sp[g]; ri[g] = rr>STK_-1?STK_-1:rr;
            a1 |= (op[g]==1); a2 |= (op[g]==2); a0 |= (op[g]==0);
        }
        const float *x0=stk[0][ti[0]], *x1=stk[1][ti[1]], *x2=stk[2][ti[2]], *x3=stk[3][ti[3]];
        if (a1) {
            float r0,r1,r2,r3; fdot4(Wd+(size_t)t*F_, x0,x1,x2,x3, F_/4, r0,r1,r2,r3);
            float bb = bd[t];
            if (op[0]==1) hh[0][t]=tanhf(r0+bb); if (op[1]==1) hh[1][t]=tanhf(r1+bb);
            if (op[2]==1) hh[2][t]=tanhf(r2+bb); if (op[3]==1) hh[3][t]=tanhf(r3+bb);
        }
        if (a2) {
            float r0,r1,r2,r3; fdot4(Wsd+(size_t)t*F_, x0,x1,x2,x3, F_/4, r0,r1,r2,r3);
            float bb = bsd[t];
            if (op[0]==2) hh[0][t]=tanhf(r0+bb); if (op[1]==2) hh[1][t]=tanhf(r1+bb);
            if (op[2]==2) hh[2][t]=tanhf(r2+bb); if (op[3]==2) hh[3][t]=tanhf(r3+bb);
        }
        if (a0 && t < FB_G*BOX_) {
            int g = t / BOX_, cc = t - g*BOX_;
            if (op[g]==0) {
                float acc = fdot1(Wbox+(size_t)cc*F_, stk[g][ti[g]], F_/4);
                boxtmp[g][bc[g]][cc] = tanhf(acc + bbox[cc]);
            }
        }
        __syncthreads();
        if (a1) {
            if (t < F_) {
                float r0,r1,r2,r3; fdot4(Wl+(size_t)t*H_, hh[0],hh[1],hh[2],hh[3], H_/4, r0,r1,r2,r3);
                float bb = bl[t];
                if (op[0]==1) stk[0][ti[0]][t]=tanhf(r0+bb); if (op[1]==1) stk[1][ti[1]][t]=tanhf(r1+bb);
                if (op[2]==1) stk[2][ti[2]][t]=tanhf(r2+bb); if (op[3]==1) stk[3][ti[3]][t]=tanhf(r3+bb);
            } else {
                int m = t - F_;
                float r0,r1,r2,r3; fdot4(Wr+(size_t)m*H_, hh[0],hh[1],hh[2],hh[3], H_/4, r0,r1,r2,r3);
                float bb = br[m];
                if (op[0]==1) stk[0][ri[0]][m]=tanhf(r0+bb); if (op[1]==1) stk[1][ri[1]][m]=tanhf(r1+bb);
                if (op[2]==1) stk[2][ri[2]][m]=tanhf(r2+bb); if (op[3]==1) stk[3][ri[3]][m]=tanhf(r3+bb);
            }
        }
        if (a2) {
            if (t < F_) {
                float r0,r1,r2,r3; fdot4(Wsf+(size_t)t*H_, hh[0],hh[1],hh[2],hh[3], H_/4, r0,r1,r2,r3);
                float bb = bsf[t];
                if (op[0]==2) stk[0][ti[0]][t]=tanhf(r0+bb); if (op[1]==2) stk[1][ti[1]][t]=tanhf(r1+bb);
                if (op[2]==2) stk[2][ti[2]][t]=tanhf(r2+bb); if (op[3]==2) stk[3][ti[3]][t]=tanhf(r3+bb);
            } else if (t < F_ + FB_G*S_) {
                int idx = t - F_, g = idx >> 3, cc = idx & 7;
                if (op[g]==2) {
                    float acc = fdot1(Wss+(size_t)cc*H_, hh[g], H_/4);
                    symtmp[g][sc[g]][cc] = tanhf(acc + bss[cc]);
                }
            }
        }
        __syncthreads();
#pragma unroll
        for (int g = 0; g < FB_G; ++g) {
            if (op[g]==1) sp[g]++;
            else if (op[g]==2) sc[g]++;
            else { bc[g]++; sp[g]--; }
        }
    }
#pragma unroll
    for (int g = 0; g < FB_G; ++g) {
        int b = b0 + g;
        float* ob = out + (size_t)b * MAXB_ * BOX_;
        for (int idx = t; idx < MAXB_*BOX_; idx += 1024) {
            int jj = idx / BOX_, cc = idx - jj*BOX_;
            int e = bc[g] - 1 - jj;
            ob[idx] = (e >= 0) ? boxtmp[g][e][cc] : 0.f;
        }
        float* os = out + (size_t)B_*MAXB_*BOX_ + (size_t)b * MAXSY_ * S_;
        for (int idx = t; idx < MAXSY_*S_; idx += 1024) {
            int jj = idx >> 3, cc = idx & 7;
            int e = sc[g] - 1 - jj;
            os[idx] = (e >= 0) ? symtmp[g][e][cc] : 0.f;
        }
    }
}

// ---------------- launcher ----------------
extern "C" void kernel_launch(void* const* d_in, const int* in_sizes, int n_in,
                              void* d_out, int out_size, void* d_ws, size_t ws_size,
                              hipStream_t stream) {
    (void)in_sizes; (void)n_in;
    const float* X    = (const float*)d_in[0];
    const int*   ops  = (const int*)d_in[1];
    const float* Wd   = (const float*)d_in[2];  const float* bd   = (const float*)d_in[3];
    const float* Wl   = (const float*)d_in[4];  const float* bl   = (const float*)d_in[5];
    const float* Wr   = (const float*)d_in[6];  const float* br   = (const float*)d_in[7];
    const float* Wsd  = (const float*)d_in[8];  const float* bsd  = (const float*)d_in[9];
    const float* Wsf  = (const float*)d_in[10]; const float* bsf  = (const float*)d_in[11];
    const float* Wss  = (const float*)d_in[12]; const float* bss  = (const float*)d_in[13];
    const float* Wbox = (const float*)d_in[14]; const float* bbox = (const float*)d_in[15];
    float* out = (float*)d_out;

    if (ws_size < WS_NEED) {
        grass_fallback<<<dim3(B_/FB_G), dim3(1024), 0, stream>>>(
            X, ops, Wd, bd, Wl, bl, Wr, br, Wsd, bsd, Wsf, bsf, Wss, bss, Wbox, bbox, out);
        return;
    }
    char* ws = (char*)d_ws;
    hipMemsetAsync(d_out, 0, (size_t)out_size * sizeof(float), stream);  // zero-pad slots
    hipMemsetAsync(ws, 0, 8192, stream);                                 // barrier counters
    grass_prep<<<dim3(512), dim3(256), 0, stream>>>(X, Wd, Wl, Wr, Wsd, Wsf, Wss, Wbox, ws);
    grass_main<<<dim3(256), dim3(256), 0, stream>>>(ops, bd, bl, br, bsd, bsf, bss, bbox, ws, out);
}